// Round 1
// baseline (564.650 us; speedup 1.0000x reference)
//
#include <hip/hip_runtime.h>
#include <math.h>

#define NN 8192
#define DD 14
#define DP 16
#define FF 2048
#define HID 256
#define LN_EPS 1e-5f
#define NCH 32      // attention key chunks
#define CHK 256     // keys per chunk
#define FCH 64      // ffn j per chunk
#define NFCH 32     // ffn chunks
#define QSCALE (1.4426950408889634f / 3.7416573867739413f)  // log2(e)/sqrt(14)
#define NEGBIG (-1e30f)

#define LOAD16(dst, srcp) { \
  const float4* _p = (const float4*)(srcp); \
  float4 _a = _p[0], _b = _p[1], _c = _p[2], _d = _p[3]; \
  dst[0]=_a.x; dst[1]=_a.y; dst[2]=_a.z; dst[3]=_a.w; \
  dst[4]=_b.x; dst[5]=_b.y; dst[6]=_b.z; dst[7]=_b.w; \
  dst[8]=_c.x; dst[9]=_c.y; dst[10]=_c.z; dst[11]=_c.w; \
  dst[12]=_d.x; dst[13]=_d.y; dst[14]=_d.z; dst[15]=_d.w; }

#define STORE16(dstp, src) { \
  float4* _p = (float4*)(dstp); \
  _p[0] = make_float4(src[0], src[1], src[2], src[3]); \
  _p[1] = make_float4(src[4], src[5], src[6], src[7]); \
  _p[2] = make_float4(src[8], src[9], src[10], src[11]); \
  _p[3] = make_float4(src[12], src[13], src[14], src[15]); }

// ---------------- copy x -> padded h ----------------
__global__ void copy_x(const float* __restrict__ x, float* __restrict__ h) {
  int r = blockIdx.x * 256 + threadIdx.x;
  float v[16];
  #pragma unroll
  for (int d = 0; d < 14; d++) v[d] = x[(size_t)r * 14 + d];
  v[14] = 0.f; v[15] = 0.f;
  STORE16(h + (size_t)r * DP, v);
}

// ---------------- qkv projection ----------------
__global__ void qkv_proj(const float* __restrict__ h, const float* __restrict__ wqkv,
                         const float* __restrict__ bqkv, float* __restrict__ Q,
                         float* __restrict__ K, float* __restrict__ V) {
  int r = blockIdx.x * 256 + threadIdx.x;
  float hr[16];
  LOAD16(hr, h + (size_t)r * DP);
  #pragma unroll 6
  for (int c = 0; c < 42; c++) {
    const float* w = wqkv + c * 14;
    float s = bqkv[c];
    #pragma unroll
    for (int d = 0; d < 14; d++) s = fmaf(hr[d], w[d], s);
    if (c < 14)       Q[(size_t)r * DP + c]        = s * QSCALE;
    else if (c < 28)  K[(size_t)r * DP + (c - 14)] = s;
    else              V[(size_t)r * DP + (c - 28)] = s;
  }
  Q[(size_t)r * DP + 14] = 0.f; Q[(size_t)r * DP + 15] = 0.f;
  K[(size_t)r * DP + 14] = 0.f; K[(size_t)r * DP + 15] = 0.f;
  V[(size_t)r * DP + 14] = 0.f; V[(size_t)r * DP + 15] = 0.f;
}

// ---------------- attention phase 1: per (row, key-chunk) partials ----------------
__global__ __launch_bounds__(256, 2) void attn_phase1(
    const float* __restrict__ Q, const float* __restrict__ Kb,
    const float* __restrict__ Vb, float* __restrict__ part) {
  __shared__ float Ks[CHK][DP];
  __shared__ float Vs[CHK][DP];
  const int tid = threadIdx.x;
  const int rowBase = blockIdx.x * 512;
  const int kBase = blockIdx.y * CHK;
  for (int idx = tid; idx < CHK * 4; idx += 256) {
    int j = idx >> 2, c = idx & 3;
    ((float4*)&Ks[j][0])[c] = ((const float4*)(Kb + (size_t)(kBase + j) * DP))[c];
    ((float4*)&Vs[j][0])[c] = ((const float4*)(Vb + (size_t)(kBase + j) * DP))[c];
  }
  __syncthreads();
  const int rA = rowBase + tid;
  const int rB = rA + 256;
  float qa[16], qb[16];
  LOAD16(qa, Q + (size_t)rA * DP);
  LOAD16(qb, Q + (size_t)rB * DP);
  float aA[16], aB[16];
  #pragma unroll
  for (int d = 0; d < 16; d++) { aA[d] = 0.f; aB[d] = 0.f; }
  float mA = NEGBIG, lA = 0.f, mB = NEGBIG, lB = 0.f;

  for (int j = 0; j < CHK; j++) {
    float kv[16];
    LOAD16(kv, &Ks[j][0]);
    float sA0=0.f,sA1=0.f,sA2=0.f,sA3=0.f,sB0=0.f,sB1=0.f,sB2=0.f,sB3=0.f;
    #pragma unroll
    for (int d = 0; d < 4; d++) {
      sA0 = fmaf(qa[d],      kv[d],      sA0);
      sA1 = fmaf(qa[d + 4],  kv[d + 4],  sA1);
      sA2 = fmaf(qa[d + 8],  kv[d + 8],  sA2);
      sA3 = fmaf(qa[d + 12], kv[d + 12], sA3);
      sB0 = fmaf(qb[d],      kv[d],      sB0);
      sB1 = fmaf(qb[d + 4],  kv[d + 4],  sB1);
      sB2 = fmaf(qb[d + 8],  kv[d + 8],  sB2);
      sB3 = fmaf(qb[d + 12], kv[d + 12], sB3);
    }
    float sA = (sA0 + sA1) + (sA2 + sA3);
    float sB = (sB0 + sB1) + (sB2 + sB3);
    float vv[16];
    LOAD16(vv, &Vs[j][0]);
    float nmA = fmaxf(mA, sA);
    float nmB = fmaxf(mB, sB);
    float pA = exp2f(sA - nmA);
    float pB = exp2f(sB - nmB);
    float scA = exp2f(mA - nmA);
    float scB = exp2f(mB - nmB);
    mA = nmA; mB = nmB;
    lA = fmaf(lA, scA, pA);
    lB = fmaf(lB, scB, pB);
    #pragma unroll
    for (int d = 0; d < 16; d++) {
      aA[d] = fmaf(aA[d], scA, pA * vv[d]);
      aB[d] = fmaf(aB[d], scB, pB * vv[d]);
    }
  }
  float oA[16], oB[16];
  oA[0] = mA; oA[1] = lA; oB[0] = mB; oB[1] = lB;
  #pragma unroll
  for (int d = 0; d < 14; d++) { oA[2 + d] = aA[d]; oB[2 + d] = aB[d]; }
  STORE16(part + ((size_t)rA * NCH + blockIdx.y) * 16, oA);
  STORE16(part + ((size_t)rB * NCH + blockIdx.y) * 16, oB);
}

// ---------------- attention combine + out-proj + residual + LN1 ----------------
__global__ void attn_combine_ln1(float* __restrict__ h, const float* __restrict__ part,
                                 const float* __restrict__ wo, const float* __restrict__ bo,
                                 const float* __restrict__ g, const float* __restrict__ b) {
  int r = blockIdx.x * 256 + threadIdx.x;
  float M = NEGBIG, L = 0.f;
  float A[14];
  #pragma unroll
  for (int d = 0; d < 14; d++) A[d] = 0.f;
  const float* pr = part + (size_t)r * NCH * 16;
  for (int c = 0; c < NCH; c++) {
    float p[16];
    LOAD16(p, pr + c * 16);
    float mc = p[0], lc = p[1];
    float nm = fmaxf(M, mc);
    float so = exp2f(M - nm);
    float sn = exp2f(mc - nm);
    M = nm;
    L = fmaf(L, so, lc * sn);
    #pragma unroll
    for (int d = 0; d < 14; d++) A[d] = fmaf(A[d], so, p[2 + d] * sn);
  }
  float inv = 1.f / L;
  float hr[16];
  LOAD16(hr, h + (size_t)r * DP);
  float a[14];
  #pragma unroll
  for (int d = 0; d < 14; d++) a[d] = A[d] * inv;
  float xx[14];
  #pragma unroll
  for (int i = 0; i < 14; i++) {
    float s = bo[i];
    #pragma unroll
    for (int d = 0; d < 14; d++) s = fmaf(wo[i * 14 + d], a[d], s);
    xx[i] = hr[i] + s;
  }
  float mu = 0.f;
  #pragma unroll
  for (int i = 0; i < 14; i++) mu += xx[i];
  mu *= (1.f / 14.f);
  float var = 0.f;
  #pragma unroll
  for (int i = 0; i < 14; i++) { float t = xx[i] - mu; var = fmaf(t, t, var); }
  var *= (1.f / 14.f);
  float rs = rsqrtf(var + LN_EPS);
  float o[16];
  #pragma unroll
  for (int i = 0; i < 14; i++) o[i] = fmaf((xx[i] - mu) * rs, g[i], b[i]);
  o[14] = 0.f; o[15] = 0.f;
  STORE16(h + (size_t)r * DP, o);
}

// ---------------- fused FFN phase 1 (partials over j-chunks) ----------------
__global__ __launch_bounds__(256, 2) void ffn_phase1(
    const float* __restrict__ h, const float* __restrict__ w1,
    const float* __restrict__ b1, const float* __restrict__ w2,
    float* __restrict__ part) {
  __shared__ float W1s[FCH][16];
  __shared__ float W2s[FCH][16];
  __shared__ float b1s[FCH];
  const int tid = threadIdx.x;
  const int jbase = blockIdx.y * FCH;
  for (int idx = tid; idx < FCH * 16; idx += 256) {
    int j = idx >> 4, d = idx & 15;
    W1s[j][d] = (d < 14) ? w1[(size_t)(jbase + j) * 14 + d] : 0.f;
    W2s[j][d] = (d < 14) ? w2[(size_t)d * FF + jbase + j] : 0.f;
  }
  if (tid < FCH) b1s[tid] = b1[jbase + tid];
  __syncthreads();
  const int rA = blockIdx.x * 512 + tid;
  const int rB = rA + 256;
  float ha[16], hb[16];
  LOAD16(ha, h + (size_t)rA * DP);
  LOAD16(hb, h + (size_t)rB * DP);
  float aA[16], aB[16];
  #pragma unroll
  for (int d = 0; d < 16; d++) { aA[d] = 0.f; aB[d] = 0.f; }
  for (int j = 0; j < FCH; j++) {
    float w1v[16];
    LOAD16(w1v, &W1s[j][0]);
    float sA0=0.f,sA1=0.f,sA2=0.f,sA3=0.f,sB0=0.f,sB1=0.f,sB2=0.f,sB3=0.f;
    #pragma unroll
    for (int d = 0; d < 4; d++) {
      sA0 = fmaf(ha[d],      w1v[d],      sA0);
      sA1 = fmaf(ha[d + 4],  w1v[d + 4],  sA1);
      sA2 = fmaf(ha[d + 8],  w1v[d + 8],  sA2);
      sA3 = fmaf(ha[d + 12], w1v[d + 12], sA3);
      sB0 = fmaf(hb[d],      w1v[d],      sB0);
      sB1 = fmaf(hb[d + 4],  w1v[d + 4],  sB1);
      sB2 = fmaf(hb[d + 8],  w1v[d + 8],  sB2);
      sB3 = fmaf(hb[d + 12], w1v[d + 12], sB3);
    }
    float tA = fmaxf(((sA0 + sA1) + (sA2 + sA3)) + b1s[j], 0.f);
    float tB = fmaxf(((sB0 + sB1) + (sB2 + sB3)) + b1s[j], 0.f);
    float w2v[16];
    LOAD16(w2v, &W2s[j][0]);
    #pragma unroll
    for (int d = 0; d < 16; d++) {
      aA[d] = fmaf(tA, w2v[d], aA[d]);
      aB[d] = fmaf(tB, w2v[d], aB[d]);
    }
  }
  STORE16(part + ((size_t)rA * NFCH + blockIdx.y) * 16, aA);
  STORE16(part + ((size_t)rB * NFCH + blockIdx.y) * 16, aB);
}

// ---------------- FFN combine + residual + LN2 ----------------
__global__ void ffn_combine_ln2(float* __restrict__ h, const float* __restrict__ part,
                                const float* __restrict__ b2, const float* __restrict__ g,
                                const float* __restrict__ b) {
  int r = blockIdx.x * 256 + threadIdx.x;
  float f[14];
  #pragma unroll
  for (int d = 0; d < 14; d++) f[d] = b2[d];
  const float* pr = part + (size_t)r * NFCH * 16;
  for (int c = 0; c < NFCH; c++) {
    float p[16];
    LOAD16(p, pr + c * 16);
    #pragma unroll
    for (int d = 0; d < 14; d++) f[d] += p[d];
  }
  float hr[16];
  LOAD16(hr, h + (size_t)r * DP);
  float xx[14];
  #pragma unroll
  for (int i = 0; i < 14; i++) xx[i] = hr[i] + f[i];
  float mu = 0.f;
  #pragma unroll
  for (int i = 0; i < 14; i++) mu += xx[i];
  mu *= (1.f / 14.f);
  float var = 0.f;
  #pragma unroll
  for (int i = 0; i < 14; i++) { float t = xx[i] - mu; var = fmaf(t, t, var); }
  var *= (1.f / 14.f);
  float rs = rsqrtf(var + LN_EPS);
  float o[16];
  #pragma unroll
  for (int i = 0; i < 14; i++) o[i] = fmaf((xx[i] - mu) * rs, g[i], b[i]);
  o[14] = 0.f; o[15] = 0.f;
  STORE16(h + (size_t)r * DP, o);
}

// ---------------- size head: fc1 -> fc2 -> size_out ----------------
__global__ void head_size(const float* __restrict__ h, const float* __restrict__ fc1w,
                          const float* __restrict__ fc1b, const float* __restrict__ fc2w,
                          const float* __restrict__ fc2b, float* __restrict__ out,
                          float* __restrict__ sizef) {
  int r = blockIdx.x * 256 + threadIdx.x;
  float hr[16];
  LOAD16(hr, h + (size_t)r * DP);
  float s = fc2b[0];
  #pragma unroll
  for (int i = 0; i < 14; i++) {
    float t = fc1b[i];
    #pragma unroll
    for (int d = 0; d < 14; d++) t = fmaf(fc1w[i * 14 + d], hr[d], t);
    s = fmaf(t, fc2w[i], s);
  }
  out[r] = s;
  int si = (int)s;  // trunc toward zero, matches astype(int32)
  sizef[r] = (float)si;
}

// ---------------- regression head: fc3 -> fc4 -> fc5, masked ----------------
__global__ __launch_bounds__(256, 2) void head_reg(
    const float* __restrict__ x, const float* __restrict__ y,
    const float* __restrict__ sizef,
    const float* __restrict__ w3, const float* __restrict__ b3,
    const float* __restrict__ w4, const float* __restrict__ b4,
    const float* __restrict__ w5, const float* __restrict__ b5,
    float* __restrict__ outr) {
  __shared__ float RT[51][16];     // reg_in transposed [k][row]
  __shared__ float R1[16][HID];
  __shared__ float R2[16][HID];
  __shared__ float red[16][4];
  const int tid = threadIdx.x;
  const int rbase = blockIdx.x * 16;
  for (int idx = tid; idx < 51 * 16; idx += 256) {
    int rr = idx & 15, k = idx >> 4;
    float v;
    if (k == 0)       v = sizef[rbase + rr];
    else if (k < 15)  v = x[(size_t)(rbase + rr) * 14 + (k - 1)];
    else              v = y[(size_t)(rbase + rr) * 36 + (k - 15)];
    RT[k][rr] = v;
  }
  __syncthreads();
  const int j = tid;
  // fc3: 51 -> 256, relu
  float acc[16];
  float bj = b3[j];
  #pragma unroll
  for (int rr = 0; rr < 16; rr++) acc[rr] = bj;
  for (int k = 0; k < 51; k++) {
    float w = w3[(size_t)j * 51 + k];
    float t[16];
    LOAD16(t, &RT[k][0]);
    #pragma unroll
    for (int rr = 0; rr < 16; rr++) acc[rr] = fmaf(t[rr], w, acc[rr]);
  }
  #pragma unroll
  for (int rr = 0; rr < 16; rr++) R1[rr][j] = fmaxf(acc[rr], 0.f);
  __syncthreads();
  // fc4: 256 -> 256, relu
  float acc2[16];
  float b4j = b4[j];
  #pragma unroll
  for (int rr = 0; rr < 16; rr++) acc2[rr] = b4j;
  const float4* w44 = (const float4*)(w4 + (size_t)j * HID);
  for (int k4 = 0; k4 < HID / 4; k4++) {
    float4 w = w44[k4];
    #pragma unroll
    for (int rr = 0; rr < 16; rr++) {
      float4 t = ((const float4*)&R1[rr][0])[k4];
      acc2[rr] = fmaf(t.x, w.x, fmaf(t.y, w.y, fmaf(t.z, w.z, fmaf(t.w, w.w, acc2[rr]))));
    }
  }
  float w5j = w5[j];
  #pragma unroll
  for (int rr = 0; rr < 16; rr++) R2[rr][j] = fmaxf(acc2[rr], 0.f) * w5j;
  __syncthreads();
  // fc5 reduce: 64 lanes, each sums a quarter-row of 64
  if (tid < 64) {
    int rr = tid >> 2, seg = tid & 3;
    const float4* r2 = (const float4*)&R2[rr][seg * 64];
    float s0 = 0.f, s1 = 0.f, s2 = 0.f, s3 = 0.f;
    #pragma unroll
    for (int q = 0; q < 16; q += 4) {
      float4 a0 = r2[q], a1 = r2[q + 1], a2 = r2[q + 2], a3 = r2[q + 3];
      s0 += (a0.x + a0.y) + (a0.z + a0.w);
      s1 += (a1.x + a1.y) + (a1.z + a1.w);
      s2 += (a2.x + a2.y) + (a2.z + a2.w);
      s3 += (a3.x + a3.y) + (a3.z + a3.w);
    }
    red[rr][seg] = (s0 + s1) + (s2 + s3);
  }
  __syncthreads();
  if (tid < 16) {
    int rr = tid;
    float val = ((red[rr][0] + red[rr][1]) + (red[rr][2] + red[rr][3])) + b5[0];
    float sz = sizef[rbase + rr];
    outr[rbase + rr] = (sz != 0.f) ? val : 0.f;
  }
}

extern "C" void kernel_launch(void* const* d_in, const int* in_sizes, int n_in,
                              void* d_out, int out_size, void* d_ws, size_t ws_size,
                              hipStream_t stream) {
  const float* x    = (const float*)d_in[0];
  const float* y    = (const float*)d_in[1];
  const float* wqkv = (const float*)d_in[2];
  const float* bqkv = (const float*)d_in[3];
  const float* wo   = (const float*)d_in[4];
  const float* bo   = (const float*)d_in[5];
  const float* ln1g = (const float*)d_in[6];
  const float* ln1b = (const float*)d_in[7];
  const float* ffw1 = (const float*)d_in[8];
  const float* ffb1 = (const float*)d_in[9];
  const float* ffw2 = (const float*)d_in[10];
  const float* ffb2 = (const float*)d_in[11];
  const float* ln2g = (const float*)d_in[12];
  const float* ln2b = (const float*)d_in[13];
  const float* fc1w = (const float*)d_in[14];
  const float* fc1b = (const float*)d_in[15];
  const float* fc2w = (const float*)d_in[16];
  const float* fc2b = (const float*)d_in[17];
  const float* fc3w = (const float*)d_in[18];
  const float* fc3b = (const float*)d_in[19];
  const float* fc4w = (const float*)d_in[20];
  const float* fc4b = (const float*)d_in[21];
  const float* fc5w = (const float*)d_in[22];
  const float* fc5b = (const float*)d_in[23];

  float* ws = (float*)d_ws;
  float* h    = ws;                       // 8192*16
  float* Q    = ws + 131072;              // 8192*16
  float* K    = ws + 262144;              // 8192*16
  float* V    = ws + 393216;              // 8192*16
  float* part = ws + 524288;              // 8192*32*16 = 4194304
  float* sizef = ws + 524288 + 4194304;   // 8192

  float* out = (float*)d_out;

  copy_x<<<32, 256, 0, stream>>>(x, h);
  for (int l = 0; l < 2; l++) {
    qkv_proj<<<32, 256, 0, stream>>>(h, wqkv + (size_t)l * 42 * 14, bqkv + (size_t)l * 42,
                                     Q, K, V);
    attn_phase1<<<dim3(16, 32), 256, 0, stream>>>(Q, K, V, part);
    attn_combine_ln1<<<32, 256, 0, stream>>>(h, part, wo + (size_t)l * 196,
                                             bo + (size_t)l * 14, ln1g + (size_t)l * 14,
                                             ln1b + (size_t)l * 14);
    ffn_phase1<<<dim3(16, 32), 256, 0, stream>>>(h, ffw1 + (size_t)l * FF * 14,
                                                 ffb1 + (size_t)l * FF,
                                                 ffw2 + (size_t)l * 14 * FF, part);
    ffn_combine_ln2<<<32, 256, 0, stream>>>(h, part, ffb2 + (size_t)l * 14,
                                            ln2g + (size_t)l * 14, ln2b + (size_t)l * 14);
  }
  head_size<<<32, 256, 0, stream>>>(h, fc1w, fc1b, fc2w, fc2b, out, sizef);
  head_reg<<<512, 256, 0, stream>>>(x, y, sizef, fc3w, fc3b, fc4w, fc4b, fc5w, fc5b,
                                    out + NN);
}